// Round 1
// 172.474 us; speedup vs baseline: 1.0476x; 1.0476x over previous
//
#include <hip/hip_runtime.h>
#include <math.h>

#define TOKENS    1024
#define IN_W      512
#define BLOCK_H   256
#define OUT_W     512
#define N_EXPERTS 64
#define TOPK      2
#define NSLOTS    (TOKENS * TOPK)
#define LIST_CAP  128     // ne ~ Binom(2048,1/64): mean 32, sigma 5.6; 128 is +17 sigma
#define T_CAP     12      // max tokens per pass (covers ne <= 48 in one pass, 99.8%)
#define NGRP      4       // groups per expert; group g takes slots g, g+4, g+8, ...
#define XPAD      520     // x row stride (floats); 2080 B, 16B-aligned, 520%32=8
#define VPAD      264     // v row stride; 1056 B, 16B-aligned, 264%32=8

// ---------------------------------------------------------------------------
// Routing + fused compaction (UNCHANGED from previous round).
// ---------------------------------------------------------------------------
__global__ __launch_bounds__(256) void routing_kernel(
    const float* __restrict__ x, const float* __restrict__ noise,
    const float* __restrict__ mixer, const float* __restrict__ noisec,
    float* __restrict__ esc, int* __restrict__ counts, int* __restrict__ lists)
{
    __shared__ float xs[2 * 512];
    __shared__ float pm[2 * 2 * 64];   // [token][half][expert] mixer partials
    __shared__ float pn[2 * 2 * 64];
    const int blk  = blockIdx.x;       // tokens 2*blk, 2*blk+1
    const int tid  = threadIdx.x;
    const int wave = tid >> 6, lane = tid & 63;
    const int tq = wave >> 1;          // token 0/1
    const int ih = wave & 1;           // i half 0/1

    ((float4*)xs)[tid] = ((const float4*)x)[(size_t)blk * 256 + tid];
    __syncthreads();

    float am = 0.f, an = 0.f;
    const float* xp = xs + tq * 512 + ih * 256;
    const float* mp = mixer  + (size_t)(ih * 256) * 64 + lane;
    const float* np = noisec + (size_t)(ih * 256) * 64 + lane;
    #pragma unroll 8
    for (int i = 0; i < 256; ++i) {
        const float xv = xp[i];                  // wave-uniform broadcast
        am = fmaf(xv, mp[i * 64], am);           // coalesced across lanes
        an = fmaf(xv, np[i * 64], an);
    }
    pm[tq * 128 + ih * 64 + lane] = am;
    pn[tq * 128 + ih * 64 + lane] = an;
    __syncthreads();

    if (tid < 128) {
        const int e = tid & 63, tt = tid >> 6;
        const int t = blk * 2 + tt;
        const float am2 = pm[tt * 128 + e] + pm[tt * 128 + 64 + e];
        const float an2 = pn[tt * 128 + e] + pn[tt * 128 + 64 + e];
        // softplus(v) = max(v,0) + log1p(exp(-|v|))
        const float sp = fmaxf(an2, 0.f) + log1pf(expf(-fabsf(an2)));
        pm[tt * 128 + e] = am2 + noise[(size_t)t * 64 + e] * sp;  // reuse as h
    }
    __syncthreads();

    if (tid < 2) {
        const float* h = pm + tid * 128;
        float b0 = -INFINITY, b1 = -INFINITY;
        int i0 = 0, i1 = 0;
        for (int i = 0; i < N_EXPERTS; ++i) {
            const float v = h[i];
            if (v > b0)      { b1 = b0; i1 = i0; b0 = v; i0 = i; }  // strict >: stable ties
            else if (v > b1) { b1 = v; i1 = i; }
        }
        const float z   = expf(b1 - b0);
        const float inv = 1.f / (1.f + z);
        const int t = blk * 2 + tid;
        esc[t * 2 + 0] = inv;
        esc[t * 2 + 1] = z * inv;
        const int p0 = atomicAdd(&counts[i0], 1);
        if (p0 < LIST_CAP) lists[i0 * LIST_CAP + p0] = t * 2 + 0;
        const int p1 = atomicAdd(&counts[i1], 1);
        if (p1 < LIST_CAP) lists[i1 * LIST_CAP + p1] = t * 2 + 1;
    }
}

// ---------------------------------------------------------------------------
// Fused expert FFN, v2: waves split COLUMNS only (weights read once per block,
// 4x L2-traffic cut vs v1), lanes split rows with shfl_xor butterfly reduce.
// Each 16B weight load feeds 4*T fmas (T up to 12) -> 4x latency tolerance.
// grid (64 experts, 4 groups); group g owns slots g, g+4, ... (balanced).
// Templated T in {4,8,12} keeps accumulator indexing static (no scratch) and
// caps zero-pad waste at <4 tokens. Phase-2 output goes straight from
// registers to global atomicAdd (no os staging, one barrier fewer).
// ---------------------------------------------------------------------------
__device__ __forceinline__ void red_xor(float4& v, int m) {
    v.x += __shfl_xor(v.x, m); v.y += __shfl_xor(v.y, m);
    v.z += __shfl_xor(v.z, m); v.w += __shfl_xor(v.w, m);
}

template<int T>
__device__ __forceinline__ void run_pass(
    int nTok, int wave, int lane,
    const float4* __restrict__ w1v, const float4* __restrict__ w2v,
    const float4* __restrict__ b1v, const float4* __restrict__ b2v,
    const float* __restrict__ xs, float* __restrict__ vsm,
    const int* __restrict__ slotIds, const float* __restrict__ escv,
    float* __restrict__ out)
{
    // ---- phase 1: v = relu(x @ W1 + b1) ----
    // wave covers cols [wave*16, wave*16+16); lane = (r0 = lane>>2, c4l = lane&3)
    // row = s*16 + r0; per instr: 16 row-chunks x 64 B = 1 KB unique weights.
    {
        const int c4l = lane & 3, r0 = lane >> 2;
        float4 acc[T];
        #pragma unroll
        for (int t = 0; t < T; ++t) acc[t] = make_float4(0.f, 0.f, 0.f, 0.f);
        const float4* wp = w1v + (size_t)(r0 * 64 + wave * 4 + c4l);
        const float*  xb = xs + r0;
        #pragma unroll 2
        for (int s = 0; s < 32; ++s) {
            const float4 w = wp[(size_t)s * 1024];   // rows s*16+r0, col f4 wave*4+c4l
            #pragma unroll
            for (int t = 0; t < T; ++t) {
                const float xv = xb[t * XPAD + s * 16];   // 16 banks, 4-lane broadcast
                acc[t].x = fmaf(xv, w.x, acc[t].x);
                acc[t].y = fmaf(xv, w.y, acc[t].y);
                acc[t].z = fmaf(xv, w.z, acc[t].z);
                acc[t].w = fmaf(xv, w.w, acc[t].w);
            }
        }
        #pragma unroll
        for (int t = 0; t < T; ++t) {      // reduce over r0 (lane bits 2..5)
            red_xor(acc[t], 4); red_xor(acc[t], 8);
            red_xor(acc[t], 16); red_xor(acc[t], 32);
        }
        if (r0 == 0) {
            const float4 bb = b1v[wave * 4 + c4l];
            #pragma unroll
            for (int t = 0; t < T; ++t) {
                float4 r;
                r.x = fmaxf(acc[t].x + bb.x, 0.f);
                r.y = fmaxf(acc[t].y + bb.y, 0.f);
                r.z = fmaxf(acc[t].z + bb.z, 0.f);
                r.w = fmaxf(acc[t].w + bb.w, 0.f);
                *(float4*)&vsm[t * VPAD + wave * 16 + c4l * 4] = r;
            }
        }
    }
    __syncthreads();

    // ---- phase 2: out += sc * (v @ W2 + b2), straight to global atomics ----
    // wave covers cols [wave*32, wave*32+32); lane = (r8 = lane>>3, c8 = lane&7)
    // row = s*8 + r8; per instr: 8 row-chunks x 128 B contiguous.
    {
        const int c8 = lane & 7, r8 = lane >> 3;
        float4 acc[T];
        #pragma unroll
        for (int t = 0; t < T; ++t) acc[t] = make_float4(0.f, 0.f, 0.f, 0.f);
        const float4* wp = w2v + (size_t)(r8 * 128 + wave * 8 + c8);
        const float*  vb = vsm + r8;
        #pragma unroll 2
        for (int s = 0; s < 32; ++s) {
            const float4 w = wp[(size_t)s * 1024];   // rows s*8+r8, col f4 wave*8+c8
            #pragma unroll
            for (int t = 0; t < T; ++t) {
                const float vv = vb[t * VPAD + s * 8];    // 8 banks, 8-lane broadcast
                acc[t].x = fmaf(vv, w.x, acc[t].x);
                acc[t].y = fmaf(vv, w.y, acc[t].y);
                acc[t].z = fmaf(vv, w.z, acc[t].z);
                acc[t].w = fmaf(vv, w.w, acc[t].w);
            }
        }
        #pragma unroll
        for (int t = 0; t < T; ++t) {      // reduce over r8 (lane bits 3..5)
            red_xor(acc[t], 8); red_xor(acc[t], 16); red_xor(acc[t], 32);
        }
        // butterfly leaves the full sum in every lane; spread the token loop
        // across r8 groups so all 64 lanes issue atomics (static t indexing).
        const float4 bb = b2v[wave * 8 + c8];
        #pragma unroll
        for (int t = 0; t < T; ++t) {
            if ((t & 7) == r8 && t < nTok) {
                const float sc = escv[t];
                float* o = out + (size_t)(slotIds[t] >> 1) * OUT_W
                               + (wave * 8 + c8) * 4;
                atomicAdd(o + 0, (acc[t].x + bb.x) * sc);
                atomicAdd(o + 1, (acc[t].y + bb.y) * sc);
                atomicAdd(o + 2, (acc[t].z + bb.z) * sc);
                atomicAdd(o + 3, (acc[t].w + bb.w) * sc);
            }
        }
    }
}

__global__ __launch_bounds__(1024, 4) void expert_kernel(
    const float* __restrict__ x,
    const float* __restrict__ w1s, const float* __restrict__ b1s,
    const float* __restrict__ w2s, const float* __restrict__ b2s,
    const int* __restrict__ counts, const int* __restrict__ lists,
    const float* __restrict__ esc, float* __restrict__ out)
{
    __shared__ __align__(16) float xs[T_CAP * XPAD];   // ~25.0 KB
    __shared__ __align__(16) float vsm[T_CAP * VPAD];  // ~12.7 KB
    __shared__ int   slotIds[T_CAP];
    __shared__ float escv[T_CAP];

    const int e  = blockIdx.x;
    const int g  = blockIdx.y;
    const int ne = min(counts[e], LIST_CAP);
    const int tid  = threadIdx.x;
    const int wave = tid >> 6, lane = tid & 63;

    const float4* w1v = (const float4*)(w1s + (size_t)e * IN_W * BLOCK_H);
    const float4* w2v = (const float4*)(w2s + (size_t)e * BLOCK_H * OUT_W);
    const float4* b1v = (const float4*)(b1s + (size_t)e * BLOCK_H);
    const float4* b2v = (const float4*)(b2s + (size_t)e * OUT_W);
    const float4* x4  = (const float4*)x;

    // pass p handles slot indices j = s0 + i*NGRP, i < T_CAP, s0 = g + p*48
    for (int s0 = g; s0 < ne; s0 += NGRP * T_CAP) {
        const int nTok  = min(T_CAP, (ne - s0 + NGRP - 1) / NGRP);
        const int Tpath = (nTok <= 4) ? 4 : (nTok <= 8) ? 8 : 12;

        if (tid < T_CAP) {
            int s = 0; float sc = 0.f;
            if (tid < nTok) { s = lists[e * LIST_CAP + s0 + tid * NGRP]; sc = esc[s]; }
            slotIds[tid] = s;
            escv[tid]    = sc;
        }
        __syncthreads();

        // stage Tpath token rows (zero-pad missing)
        for (int idx = tid; idx < Tpath * 128; idx += 1024) {
            const int t = idx >> 7, q = idx & 127;
            float4 v = make_float4(0.f, 0.f, 0.f, 0.f);
            if (t < nTok) v = x4[(size_t)(slotIds[t] >> 1) * 128 + q];
            *(float4*)&xs[t * XPAD + q * 4] = v;
        }
        __syncthreads();

        if (nTok <= 4)
            run_pass<4>(nTok, wave, lane, w1v, w2v, b1v, b2v, xs, vsm, slotIds, escv, out);
        else if (nTok <= 8)
            run_pass<8>(nTok, wave, lane, w1v, w2v, b1v, b2v, xs, vsm, slotIds, escv, out);
        else
            run_pass<12>(nTok, wave, lane, w1v, w2v, b1v, b2v, xs, vsm, slotIds, escv, out);
        __syncthreads();   // xs/vsm reused next pass (rare: ne > 48)
    }
}

extern "C" void kernel_launch(void* const* d_in, const int* in_sizes, int n_in,
                              void* d_out, int out_size, void* d_ws, size_t ws_size,
                              hipStream_t stream) {
    const float* x      = (const float*)d_in[0];
    const float* noise  = (const float*)d_in[1];
    const float* w1s    = (const float*)d_in[2];
    const float* b1s    = (const float*)d_in[3];
    const float* w2s    = (const float*)d_in[4];
    const float* b2s    = (const float*)d_in[5];
    const float* mixer  = (const float*)d_in[6];
    const float* noisec = (const float*)d_in[7];
    float* out = (float*)d_out;

    // workspace: ~41 KB total (keep FAR under ws_size)
    char* ws = (char*)d_ws;
    int*   counts = (int*)ws;                       ws += 256;
    float* esc    = (float*)ws;                     ws += NSLOTS * sizeof(float);
    int*   lists  = (int*)ws;   /* 64 * 128 ints = 32 KB */

    hipMemsetAsync(d_out, 0, (size_t)out_size * sizeof(float), stream);
    hipMemsetAsync(counts, 0, 256, stream);

    routing_kernel<<<TOKENS / 2, 256, 0, stream>>>(x, noise, mixer, noisec,
                                                   esc, counts, lists);
    expert_kernel<<<dim3(N_EXPERTS, NGRP), 1024, 0, stream>>>(
        x, w1s, b1s, w2s, b2s, counts, lists, esc, out);
}